// Round 15
// baseline (367.976 us; speedup 1.0000x reference)
//
#include <hip/hip_runtime.h>

// TrueEpisodicMemory round 15: q-read granularity 256B -> 512B per row per instruction.
// 32-row blocks (128 thr, 2 waves); Q windows of 128 f32 cols, double-buffered (32 KB);
// each gl16 = 2 rows x 512 B contiguous. K staging/read, softmax, P, V, PV step shape
// (64-col, 256-B out granule), NT scalar stores: r14 VERBATIM (w-range adjusted).
// Granularity ladder measured so far: 64B=318us, 128B=296us, 256B=270us.
// out[b,:] = softmax_m(q[b]·mk[m] + 0.5*cx[b]·mc[m] + exp(0.1*ts[m])) · mv
// B=131072, M=100 (pad 112/128), D=1024, C=16.

typedef __attribute__((ext_vector_type(8))) _Float16 f16x8;
typedef __attribute__((ext_vector_type(4))) float f32x4;

constexpr int DQ = 1024, CD = 16, MM = 100, KD = 1056, NT = 7;
constexpr size_t KE = (size_t)112 * KD;

// LDS (bytes):
//  QK: Q[2][32 rows][32 slots x16B] @0 (16 KB ea -> 32768); K[3][112][4 slots x16B]
//      @32768 (7168 ea -> 21504; end 54272).
//  PV overlay: P[2 waves][4096] @0 (8192); V[3][64 rows][16 slots x16B] @8192
//      (16384 ea -> 49152; end 57344).
constexpr int QBUF = 16384, KOFF = 32768, KBUF = 7168;
constexpr int VOFF = 8192, VBUF = 16384;
constexpr int LDSZ = 57344;

#define WAITV(n) asm volatile("s_waitcnt vmcnt(" #n ")" ::: "memory")

__device__ __forceinline__ void gl16(const void* g, void* l) {
    __builtin_amdgcn_global_load_lds(
        (const __attribute__((address_space(1))) unsigned int*)g,
        (__attribute__((address_space(3))) unsigned int*)l, 16, 0, 0);
}

// ---------------- prologue: fp16 K [112][1056], ctx folded at cols 1024..1039 (r11) ----------
__global__ void build_k(const float* __restrict__ mk, const float* __restrict__ mc,
                        _Float16* __restrict__ KH)
{
    int d = blockIdx.x * 64 + threadIdx.x;
    int m = blockIdx.y;
    if (d >= KD) return;
    float x = 0.f;
    if (m < MM) {
        if (d < DQ)            x = mk[(size_t)m * DQ + d];
        else if (d < DQ + CD)  x = 0.5f * mc[(size_t)m * CD + (d - DQ)];
    }
    KH[(size_t)m * KD + d] = (_Float16)x;
}

// ---------------- prologue: fp16 V^T [1024][128] (cols 100..127 zero) (r11) ----------------
__global__ void build_vt(const float* __restrict__ mv, _Float16* __restrict__ VT)
{
    int idx = blockIdx.x * 256 + threadIdx.x;   // 0..131071
    int d = idx >> 7, m = idx & 127;
    VT[idx] = (m < MM) ? (_Float16)mv[(size_t)m * DQ + d] : (_Float16)0.f;
}

// ---------------- main fused kernel: 128 threads, 32 rows/block ----------------
__global__ __launch_bounds__(128, 1)
void epmem_pipe(const float* __restrict__ q, const float* __restrict__ cx,
                const float* __restrict__ ts,
                const _Float16* __restrict__ KH, const _Float16* __restrict__ VT,
                float* __restrict__ out)
{
    __shared__ __align__(16) char lds[LDSZ];

    const int t = threadIdx.x, w = t >> 6, lane = t & 63;
    const int lr = lane & 15, lk = lane >> 4;
    const int row0 = blockIdx.x * 32;
    const int key = (w * 16 + lr) & 31;         // full-row Q swizzle key

    float dec[NT];
    #pragma unroll
    for (int nt = 0; nt < NT; ++nt) {
        int m = nt * 16 + lr;
        dec[nt] = (m < MM) ? __expf(0.1f * ts[m]) : 0.f;
    }

    // ---- staging: linear LDS dest; swizzle on GLOBAL source ----
    auto stageQpart = [&](int buf, int W, int h) {  // part h of [32 rows][32 slots]: 2 instrs
        char* dst = lds + buf * QBUF;               // each instr: 2 rows x 512 B contiguous
        #pragma unroll
        for (int j = 2 * h; j < 2 * h + 2; ++j) {
            int s = j * 128 + t;                    // seg: row s>>5, phys slot s&31
            int row = s >> 5;
            int logical = (s & 31) ^ (row & 31);
            gl16(q + (size_t)(row0 + row) * DQ + W * 128 + logical * 4,
                 dst + (j * 128 + w * 64) * 16);
        }
    };
    auto stageQctx = [&]() {                        // [32 rows][4 slots] packed -> buf 0
        gl16(cx + (size_t)(row0 + (t >> 2)) * CD + (t & 3) * 4, lds + (w * 64) * 16);
    };
    auto stageK = [&](int buf, int ks) {            // 448 segs; w0: 4 instrs, w1: 3
        char* dst = lds + KOFF + buf * KBUF;
        for (int i = w; i < 7; i += 2) {
            int s = i * 64 + lane;                  // m s>>2, phys slot s&3
            int m = s >> 2;
            int logical = (s & 3) ^ ((m >> 1) & 3);
            gl16(KH + (size_t)m * KD + ks * 32 + logical * 8, dst + (i * 64) * 16);
        }
    };
    auto stageV = [&](int buf, int c) {             // [64 d][16 slots], 1024 segs, 8/thread
        char* dst = lds + VOFF + buf * VBUF;
        #pragma unroll
        for (int i = 0; i < 8; ++i) {
            int s = i * 128 + t;                    // d s>>4, phys slot s&15
            int d = s >> 4;
            int logical = (s & 15) ^ (d & 15);
            gl16(VT + (size_t)(c * 64 + d) * 128 + logical * 8,
                 dst + (i * 128 + w * 64) * 16);
        }
    };

    f32x4 acc[NT];
    #pragma unroll
    for (int nt = 0; nt < NT; ++nt) acc[nt] = (f32x4){0.f, 0.f, 0.f, 0.f};

    auto qkStep = [&](const char* qx, const char* qy, const char* kb) {
        f32x4 x = *(const f32x4*)qx, y = *(const f32x4*)qy;
        f16x8 ah, al;
        #pragma unroll
        for (int e = 0; e < 4; ++e) {
            _Float16 h = (_Float16)x[e]; ah[e] = h;     al[e] = (_Float16)(x[e] - (float)h);
            h = (_Float16)y[e];          ah[4 + e] = h; al[4 + e] = (_Float16)(y[e] - (float)h);
        }
        #pragma unroll
        for (int nt = 0; nt < NT; ++nt) {
            int m = nt * 16 + lr;
            f16x8 bh = *(const f16x8*)(kb + ((m << 2) + (lk ^ ((lr >> 1) & 3))) * 16);
            acc[nt] = __builtin_amdgcn_mfma_f32_16x16x32_f16(ah, bh, acc[nt], 0, 0, 0);
            acc[nt] = __builtin_amdgcn_mfma_f32_16x16x32_f16(al, bh, acc[nt], 0, 0, 0);
        }
    };

    // ---------- QK^T: 8 windows x 4 sub-steps (+ ctx). Prologue queue (w0/w1):
    // [Q0 x8, K0 x4/3, K1 x4/3]; need Q0,K0 -> newer = K1 -> WAITV(4)/(3). ----------
    stageQpart(0, 0, 0); stageQpart(0, 0, 1); stageQpart(0, 0, 2); stageQpart(0, 0, 3);
    stageK(0, 0); stageK(1, 1);
    if (w == 0) { WAITV(4); } else { WAITV(3); }
    __builtin_amdgcn_s_barrier();

    for (int ss = 0; ss < 32; ++ss) {
        const int ms = ss >> 2, h = ss & 3;
        if (ss < 28)       stageQpart((ms + 1) & 1, ms + 1, h);
        else if (ss == 28) stageQctx();
        if (ss <= 30)      stageK((ss + 2) % 3, ss + 2);

        const char* base = lds + (ms & 1) * QBUF + (w * 16 + lr) * 512;
        const int u0 = h * 8 + 2 * lk;
        qkStep(base + ((u0 ^ key) << 4), base + (((u0 + 1) ^ key) << 4),
               lds + KOFF + (ss % 3) * KBUF);

        // Ledger (queue-enumerated, w0/w1):
        //  ss<=27, h<3:  need K(ss+1) (last of ss-1); newer = Q2+K(4/3) -> 6/5
        //  ss<=27, h==3: need K(ss+1) AND window ms+1 (Q part this ss, before K);
        //                newer = K(ss+2) -> 4/3
        //  ss==28: need K(29) (staged at 27); newer = ctx1+K(30) -> 5/4
        //  ss==29: need K(30); newer = K(31) -> 4/3
        //  ss==30: need K(31); newer = K(32) -> 4/3
        //  ss==31: need K(32)+ctx -> 0
        if (ss <= 27) {
            if (h == 3) { if (w == 0) { WAITV(4); } else { WAITV(3); } }
            else        { if (w == 0) { WAITV(6); } else { WAITV(5); } }
        }
        else if (ss == 28) { if (w == 0) { WAITV(5); } else { WAITV(4); } }
        else if (ss <= 30) { if (w == 0) { WAITV(4); } else { WAITV(3); } }
        else               { WAITV(0); }
        __builtin_amdgcn_s_barrier();
    }
    {   // ctx sub-step: Q buf 0 packed [32][4 slots], K buf 32%3 = 2 (r14 verbatim)
        f16x8 ah, al;
        if (lk < 2) {
            const char* base = lds + (w * 16 + lr) * 64;
            f32x4 x = *(const f32x4*)(base + (2 * lk) * 16);
            f32x4 y = *(const f32x4*)(base + (2 * lk + 1) * 16);
            #pragma unroll
            for (int e = 0; e < 4; ++e) {
                _Float16 h = (_Float16)x[e]; ah[e] = h;     al[e] = (_Float16)(x[e] - (float)h);
                h = (_Float16)y[e];          ah[4 + e] = h; al[4 + e] = (_Float16)(y[e] - (float)h);
            }
        } else {
            #pragma unroll
            for (int e = 0; e < 8; ++e) { ah[e] = (_Float16)0.f; al[e] = (_Float16)0.f; }
        }
        const char* kb = lds + KOFF + 2 * KBUF;
        #pragma unroll
        for (int nt = 0; nt < NT; ++nt) {
            int m = nt * 16 + lr;
            f16x8 bh = *(const f16x8*)(kb + ((m << 2) + (lk ^ ((lr >> 1) & 3))) * 16);
            acc[nt] = __builtin_amdgcn_mfma_f32_16x16x32_f16(ah, bh, acc[nt], 0, 0, 0);
            acc[nt] = __builtin_amdgcn_mfma_f32_16x16x32_f16(al, bh, acc[nt], 0, 0, 0);
        }
    }
    __syncthreads();                            // QK LDS dead; P/V may overlay

    stageV(0, 0); stageV(1, 1);                 // V latency hides under softmax

    // ---------- softmax, fully in-register (r14 verbatim; wave owns rows w*16..+15) ----------
    char* Pb = lds + w * 4096;
    {
        float rm[4] = {-3e38f, -3e38f, -3e38f, -3e38f};
        #pragma unroll
        for (int nt = 0; nt < NT; ++nt) {
            int m = nt * 16 + lr;
            #pragma unroll
            for (int r = 0; r < 4; ++r) {
                float s = (m < MM) ? (acc[nt][r] + dec[nt]) : -3e38f;
                acc[nt][r] = s;
                rm[r] = fmaxf(rm[r], s);
            }
        }
        #pragma unroll
        for (int r = 0; r < 4; ++r)
            #pragma unroll
            for (int off = 1; off < 16; off <<= 1)
                rm[r] = fmaxf(rm[r], __shfl_xor(rm[r], off));
        float rs[4] = {0.f, 0.f, 0.f, 0.f};
        #pragma unroll
        for (int nt = 0; nt < NT; ++nt)
            #pragma unroll
            for (int r = 0; r < 4; ++r) {
                float e = __expf(acc[nt][r] - rm[r]);
                acc[nt][r] = e;
                rs[r] += e;
            }
        #pragma unroll
        for (int r = 0; r < 4; ++r)
            #pragma unroll
            for (int off = 1; off < 16; off <<= 1)
                rs[r] += __shfl_xor(rs[r], off);
        #pragma unroll
        for (int r = 0; r < 4; ++r) {
            float inv = 1.f / rs[r];
            int row = 4 * lk + r;
            #pragma unroll
            for (int nt = 0; nt < NT; ++nt)
                *(_Float16*)(Pb + row * 256 + (((nt * 2 + (lr >> 3)) ^ row) & 15) * 16
                             + (lr & 7) * 2) = (_Float16)(acc[nt][r] * inv);
        }
    }
    if (lane < 32) {                            // zero-pad P cols 112..127 (slots 14,15)
        int row = lane >> 1, sl = 14 + (lane & 1);
        uint4 z = {0u, 0u, 0u, 0u};
        *(uint4*)(Pb + row * 256 + ((sl ^ row) & 15) * 16) = z;
    }
    WAITV(8);                                   // V(0) done; newer = V(1) x8
    __builtin_amdgcn_s_barrier();

    // ---------- PV: 16 steps of 64 cols, depth-3 (r14 verbatim; 8-instr stage) ----------
    f16x8 pa[4];
    #pragma unroll
    for (int k4 = 0; k4 < 4; ++k4)
        pa[k4] = *(const f16x8*)(Pb + lr * 256 + (((k4 * 4 + lk) ^ lr) & 15) * 16);

    for (int c = 0; c < 16; ++c) {
        if (c + 2 < 16) stageV((c + 2) % 3, c + 2);
        const char* vb = lds + VOFF + (c % 3) * VBUF;
        f32x4 o0 = {0.f,0.f,0.f,0.f}, o1 = {0.f,0.f,0.f,0.f};
        f32x4 o2 = {0.f,0.f,0.f,0.f}, o3 = {0.f,0.f,0.f,0.f};
        #pragma unroll
        for (int k4 = 0; k4 < 4; ++k4) {
            const char* vb2 = vb + (((k4 * 4 + lk) ^ lr) & 15) * 16;
            f16x8 b0 = *(const f16x8*)(vb2 + lr * 256);
            f16x8 b1 = *(const f16x8*)(vb2 + (16 + lr) * 256);
            f16x8 b2 = *(const f16x8*)(vb2 + (32 + lr) * 256);
            f16x8 b3 = *(const f16x8*)(vb2 + (48 + lr) * 256);   // (d&15)=lr for all
            o0 = __builtin_amdgcn_mfma_f32_16x16x32_f16(pa[k4], b0, o0, 0, 0, 0);
            o1 = __builtin_amdgcn_mfma_f32_16x16x32_f16(pa[k4], b1, o1, 0, 0, 0);
            o2 = __builtin_amdgcn_mfma_f32_16x16x32_f16(pa[k4], b2, o2, 0, 0, 0);
            o3 = __builtin_amdgcn_mfma_f32_16x16x32_f16(pa[k4], b3, o3, 0, 0, 0);
        }
        #pragma unroll
        for (int r = 0; r < 4; ++r) {
            size_t rw = (size_t)(row0 + w * 16 + 4 * lk + r) * DQ + c * 64;
            __builtin_nontemporal_store(o0[r], &out[rw + lr]);
            __builtin_nontemporal_store(o1[r], &out[rw + 16 + lr]);
            __builtin_nontemporal_store(o2[r], &out[rw + 32 + lr]);
            __builtin_nontemporal_store(o3[r], &out[rw + 48 + lr]);
        }
        // Ledger (stage 8 first, then 16 stores per step):
        //  c=0: V(1) last of prologue -> newer = step-0 ops 8+16 -> WAITV(24)
        //  1<=c<=13: V(c+1) first of step c-1 -> newer = 16 + 8 + 16 -> WAITV(40)
        //  c=14: no stage -> newer = stores(13) 16 + stores(14) 16 -> WAITV(32)
        if (c == 0)       { WAITV(24); }
        else if (c <= 13) { WAITV(40); }
        else if (c == 14) { WAITV(32); }
        if (c < 15) __builtin_amdgcn_s_barrier();
    }
}

extern "C" void kernel_launch(void* const* d_in, const int* in_sizes, int n_in,
                              void* d_out, int out_size, void* d_ws, size_t ws_size,
                              hipStream_t stream) {
    const float* q  = (const float*)d_in[0];
    const float* cx = (const float*)d_in[1];
    const float* mk = (const float*)d_in[2];
    const float* mv = (const float*)d_in[3];
    const float* mc = (const float*)d_in[4];
    const float* ts = (const float*)d_in[5];
    float* out = (float*)d_out;

    _Float16* wsp = (_Float16*)d_ws;
    _Float16* KH = wsp;                        // [112][1056]
    _Float16* VT = wsp + KE;                   // [1024][128]

    const int B = in_sizes[0] / DQ;            // 131072

    build_k<<<dim3(17, 112), dim3(64), 0, stream>>>(mk, mc, KH);
    build_vt<<<dim3(512), dim3(256), 0, stream>>>(mv, VT);
    epmem_pipe<<<dim3(B / 32), dim3(128), 0, stream>>>(q, cx, ts, KH, VT, out);
}

// Round 17
// 274.287 us; speedup vs baseline: 1.3416x; 1.3416x over previous
//
#include <hip/hip_runtime.h>

// TrueEpisodicMemory round 17: r16 with the V-buffer OVERLAP BUG fixed (r16 put 32-KB V1
// @0 and 32-KB V0 @16384 inside 54272 B -> 16 KB overlap -> staging corrupted live V).
// Now V0 @32768, V1 @0, LDSZ = 65536 (r14's exact proven size; buffers disjoint).
// Change under test (vs r14, 270us): PV steps 64 -> 128 cols = 512-B out runs per row
// (write-granularity octave; measured read ladder: 64B=318, 128B=296, 256B=270us).
// QK phase / softmax / P / pa / store pattern: r14 VERBATIM.
// out[b,:] = softmax_m(q[b]·mk[m] + 0.5*cx[b]·mc[m] + exp(0.1*ts[m])) · mv
// B=131072, M=100 (pad 112/128), D=1024, C=16.

typedef __attribute__((ext_vector_type(8))) _Float16 f16x8;
typedef __attribute__((ext_vector_type(4))) float f32x4;

constexpr int DQ = 1024, CD = 16, MM = 100, KD = 1056, NT = 7;
constexpr size_t KE = (size_t)112 * KD;

// LDS (bytes):
//  QK: Q[2][64 rows][16 slots x16B] @0 (16 KB ea -> 32768); K[3][112][4 slots x16B]
//      @32768 (7168 ea -> 21504; end 54272).
//  PV overlay: P[4 waves][4096] @0 (16 KB, transient); V0 @32768 (32 KB, 32768..65536,
//      over dead K); V1 @0 (32 KB, 0..32768, over dead P/Q after pa consumed). Disjoint.
constexpr int QBUF = 16384, KOFF = 32768, KBUF = 7168;
constexpr int V0OFF = 32768, V1OFF = 0;
constexpr int LDSZ = 65536;

#define WAITV(n) asm volatile("s_waitcnt vmcnt(" #n ")" ::: "memory")

__device__ __forceinline__ void gl16(const void* g, void* l) {
    __builtin_amdgcn_global_load_lds(
        (const __attribute__((address_space(1))) unsigned int*)g,
        (__attribute__((address_space(3))) unsigned int*)l, 16, 0, 0);
}

// ---------------- prologue: fp16 K [112][1056], ctx folded at cols 1024..1039 (r11) ----------
__global__ void build_k(const float* __restrict__ mk, const float* __restrict__ mc,
                        _Float16* __restrict__ KH)
{
    int d = blockIdx.x * 64 + threadIdx.x;
    int m = blockIdx.y;
    if (d >= KD) return;
    float x = 0.f;
    if (m < MM) {
        if (d < DQ)            x = mk[(size_t)m * DQ + d];
        else if (d < DQ + CD)  x = 0.5f * mc[(size_t)m * CD + (d - DQ)];
    }
    KH[(size_t)m * KD + d] = (_Float16)x;
}

// ---------------- prologue: fp16 V^T [1024][128] (cols 100..127 zero) (r11) ----------------
__global__ void build_vt(const float* __restrict__ mv, _Float16* __restrict__ VT)
{
    int idx = blockIdx.x * 256 + threadIdx.x;   // 0..131071
    int d = idx >> 7, m = idx & 127;
    VT[idx] = (m < MM) ? (_Float16)mv[(size_t)m * DQ + d] : (_Float16)0.f;
}

// ---------------- main fused kernel: 256 threads, 64 rows/block ----------------
__global__ __launch_bounds__(256, 2)
void epmem_pipe(const float* __restrict__ q, const float* __restrict__ cx,
                const float* __restrict__ ts,
                const _Float16* __restrict__ KH, const _Float16* __restrict__ VT,
                float* __restrict__ out)
{
    __shared__ __align__(16) char lds[LDSZ];

    const int t = threadIdx.x, w = t >> 6, lane = t & 63;
    const int lr = lane & 15, lk = lane >> 4;
    const int row0 = blockIdx.x * 64;

    float dec[NT];
    #pragma unroll
    for (int nt = 0; nt < NT; ++nt) {
        int m = nt * 16 + lr;
        dec[nt] = (m < MM) ? __expf(0.1f * ts[m]) : 0.f;
    }

    // ---- staging: linear LDS dest; swizzle on GLOBAL source (r14 verbatim) ----
    auto stageQ = [&](int buf, int ms) {            // [64 rows][16 slots], 1024 segs, 4/thread
        char* dst = lds + buf * QBUF;               // each instr: 4 rows x 256 B contiguous
        #pragma unroll
        for (int i = 0; i < 4; ++i) {
            int s = i * 256 + t;                    // row s>>4, phys slot s&15
            int row = s >> 4;
            int logical = (s & 15) ^ (row & 15);
            gl16(q + (size_t)(row0 + row) * DQ + ms * 64 + logical * 4,
                 dst + (i * 256 + w * 64) * 16);
        }
    };
    auto stageQctx = [&](int buf) {                 // [64 rows][4 slots] packed, 256 segs
        char* dst = lds + buf * QBUF;
        gl16(cx + (size_t)(row0 + (t >> 2)) * CD + (t & 3) * 4, dst + (w * 64) * 16);
    };
    auto stageK = [&](int buf, int ks) {            // 448 segs, 7 instrs: w0..w2 x2, w3 x1
        char* dst = lds + KOFF + buf * KBUF;
        for (int i = w; i < 7; i += 4) {
            int s = i * 64 + lane;                  // m s>>2, phys slot s&3
            int m = s >> 2;
            int logical = (s & 3) ^ ((m >> 1) & 3);
            gl16(KH + (size_t)m * KD + ks * 32 + logical * 8, dst + (i * 64) * 16);
        }
    };
    auto stageV = [&](char* dst, int c) {           // [128 d][16 slots], 2048 segs, 8/thread
        #pragma unroll
        for (int i = 0; i < 8; ++i) {
            int s = i * 256 + t;                    // d s>>4 (0..127), phys slot s&15
            int d = s >> 4;
            int logical = (s & 15) ^ (d & 15);
            gl16(VT + (size_t)(c * 128 + d) * 128 + logical * 8,
                 dst + (i * 256 + w * 64) * 16);
        }
    };

    f32x4 acc[NT];
    #pragma unroll
    for (int nt = 0; nt < NT; ++nt) acc[nt] = (f32x4){0.f, 0.f, 0.f, 0.f};

    auto qkStep = [&](const char* qx, const char* qy, const char* kb) {
        f32x4 x = *(const f32x4*)qx, y = *(const f32x4*)qy;
        f16x8 ah, al;
        #pragma unroll
        for (int e = 0; e < 4; ++e) {
            _Float16 h = (_Float16)x[e]; ah[e] = h;     al[e] = (_Float16)(x[e] - (float)h);
            h = (_Float16)y[e];          ah[4 + e] = h; al[4 + e] = (_Float16)(y[e] - (float)h);
        }
        #pragma unroll
        for (int nt = 0; nt < NT; ++nt) {
            int m = nt * 16 + lr;
            f16x8 bh = *(const f16x8*)(kb + ((m << 2) + (lk ^ ((lr >> 1) & 3))) * 16);
            acc[nt] = __builtin_amdgcn_mfma_f32_16x16x32_f16(ah, bh, acc[nt], 0, 0, 0);
            acc[nt] = __builtin_amdgcn_mfma_f32_16x16x32_f16(al, bh, acc[nt], 0, 0, 0);
        }
    };

    // ---------- QK^T (r14 verbatim): 32 sub-steps of 32 k-cols + ctx sub-step ----------
    stageQ(0, 0);
    stageK(0, 0); stageK(1, 1);
    if (w < 3) { WAITV(2); } else { WAITV(1); }
    __builtin_amdgcn_s_barrier();

    for (int ss = 0; ss < 32; ++ss) {
        const int ms = ss >> 1, h = ss & 1;
        if (h == 0) {
            if (ms + 1 <= 15)   stageQ((ms + 1) & 1, ms + 1);
            else                stageQctx(0);       // ss == 30
        }
        if (ss <= 30) stageK((ss + 2) % 3, ss + 2);

        const char* base = lds + (ms & 1) * QBUF + (w * 16 + lr) * 256;
        const int u0 = h * 8 + 2 * lk;
        qkStep(base + ((u0 ^ lr) << 4), base + (((u0 + 1) ^ lr) << 4),
               lds + KOFF + (ss % 3) * KBUF);

        if (h == 0) {
            if (ss == 30) { if (w < 3) { WAITV(3); } else { WAITV(2); } }
            else          { if (w < 3) { WAITV(6); } else { WAITV(5); } }
        } else {
            if (ss == 31) { WAITV(0); }
            else          { if (w < 3) { WAITV(2); } else { WAITV(1); } }
        }
        __builtin_amdgcn_s_barrier();
    }
    {   // ctx sub-step (ss=32): r14 verbatim
        f16x8 ah, al;
        if (lk < 2) {
            const char* base = lds + (w * 16 + lr) * 64;
            f32x4 x = *(const f32x4*)(base + (2 * lk) * 16);
            f32x4 y = *(const f32x4*)(base + (2 * lk + 1) * 16);
            #pragma unroll
            for (int e = 0; e < 4; ++e) {
                _Float16 h = (_Float16)x[e]; ah[e] = h;     al[e] = (_Float16)(x[e] - (float)h);
                h = (_Float16)y[e];          ah[4 + e] = h; al[4 + e] = (_Float16)(y[e] - (float)h);
            }
        } else {
            #pragma unroll
            for (int e = 0; e < 8; ++e) { ah[e] = (_Float16)0.f; al[e] = (_Float16)0.f; }
        }
        const char* kb = lds + KOFF + 2 * KBUF;
        #pragma unroll
        for (int nt = 0; nt < NT; ++nt) {
            int m = nt * 16 + lr;
            f16x8 bh = *(const f16x8*)(kb + ((m << 2) + (lk ^ ((lr >> 1) & 3))) * 16);
            acc[nt] = __builtin_amdgcn_mfma_f32_16x16x32_f16(ah, bh, acc[nt], 0, 0, 0);
            acc[nt] = __builtin_amdgcn_mfma_f32_16x16x32_f16(al, bh, acc[nt], 0, 0, 0);
        }
    }
    __syncthreads();                            // QK LDS dead (incl. K @32768..54272)

    stageV(lds + V0OFF, 0);                     // V(0) @32768..65536; hides under softmax

    // ---------- softmax, fully in-register (r14 verbatim; Pb @ w*4096) ----------
    char* Pb = lds + w * 4096;
    {
        float rm[4] = {-3e38f, -3e38f, -3e38f, -3e38f};
        #pragma unroll
        for (int nt = 0; nt < NT; ++nt) {
            int m = nt * 16 + lr;
            #pragma unroll
            for (int r = 0; r < 4; ++r) {
                float s = (m < MM) ? (acc[nt][r] + dec[nt]) : -3e38f;
                acc[nt][r] = s;
                rm[r] = fmaxf(rm[r], s);
            }
        }
        #pragma unroll
        for (int r = 0; r < 4; ++r)
            #pragma unroll
            for (int off = 1; off < 16; off <<= 1)
                rm[r] = fmaxf(rm[r], __shfl_xor(rm[r], off));
        float rs[4] = {0.f, 0.f, 0.f, 0.f};
        #pragma unroll
        for (int nt = 0; nt < NT; ++nt)
            #pragma unroll
            for (int r = 0; r < 4; ++r) {
                float e = __expf(acc[nt][r] - rm[r]);
                acc[nt][r] = e;
                rs[r] += e;
            }
        #pragma unroll
        for (int r = 0; r < 4; ++r)
            #pragma unroll
            for (int off = 1; off < 16; off <<= 1)
                rs[r] += __shfl_xor(rs[r], off);
        #pragma unroll
        for (int r = 0; r < 4; ++r) {
            float inv = 1.f / rs[r];
            int row = 4 * lk + r;
            #pragma unroll
            for (int nt = 0; nt < NT; ++nt)
                *(_Float16*)(Pb + row * 256 + (((nt * 2 + (lr >> 3)) ^ row) & 15) * 16
                             + (lr & 7) * 2) = (_Float16)(acc[nt][r] * inv);
        }
    }
    if (lane < 32) {                            // zero-pad P cols 112..127 (slots 14,15)
        int row = lane >> 1, sl = 14 + (lane & 1);
        uint4 z = {0u, 0u, 0u, 0u};
        *(uint4*)(Pb + row * 256 + ((sl ^ row) & 15) * 16) = z;
    }

    // pa loads (wave-private P -> registers) BEFORE V(1) may overwrite the P region
    f16x8 pa[4];
    #pragma unroll
    for (int k4 = 0; k4 < 4; ++k4)
        pa[k4] = *(const f16x8*)(Pb + lr * 256 + (((k4 * 4 + lk) ^ lr) & 15) * 16);
    asm volatile("s_waitcnt lgkmcnt(0)" ::: "memory");  // pa reads complete before barrier
    WAITV(0);                                   // V(0) resident (one-time drain per block)
    __builtin_amdgcn_s_barrier();               // all waves' pa done -> @0 reusable

    // ---------- PV: 8 steps of 128 cols (512-B out runs), dbuf distance-1 ----------
    // buffers: step c computes from (c even ? V0OFF : V1OFF); stages c+1 into the other.
    for (int c = 0; c < 8; ++c) {
        if (c < 7) stageV(lds + ((c & 1) ? V0OFF : V1OFF), c + 1);
        const char* vb = lds + ((c & 1) ? V1OFF : V0OFF);
        f32x4 o[8];
        #pragma unroll
        for (int n = 0; n < 8; ++n) o[n] = (f32x4){0.f, 0.f, 0.f, 0.f};
        #pragma unroll
        for (int k4 = 0; k4 < 4; ++k4) {
            const char* vb2 = vb + (((k4 * 4 + lk) ^ lr) & 15) * 16;
            #pragma unroll
            for (int n = 0; n < 8; ++n) {           // d-local = n*16+lr; (d&15)=lr
                f16x8 bv = *(const f16x8*)(vb2 + (n * 16 + lr) * 256);
                o[n] = __builtin_amdgcn_mfma_f32_16x16x32_f16(pa[k4], bv, o[n], 0, 0, 0);
            }
        }
        #pragma unroll
        for (int n = 0; n < 8; ++n) {
            #pragma unroll
            for (int r = 0; r < 4; ++r) {
                size_t rw = (size_t)(row0 + w * 16 + 4 * lk + r) * DQ + c * 128 + n * 16;
                __builtin_nontemporal_store(o[n][r], &out[rw + lr]);
            }
        }
        // Ledger (induction: at step start <=32 stores(c-1) in flight): step issues
        // V(c+1) x8 then stores x32; WAITV(32) completes stores(c-1) + V(c+1), leaving
        // only this step's 32 stores -> V(c+1) resident before next step.
        if (c < 7) { WAITV(32); __builtin_amdgcn_s_barrier(); }
    }
}

extern "C" void kernel_launch(void* const* d_in, const int* in_sizes, int n_in,
                              void* d_out, int out_size, void* d_ws, size_t ws_size,
                              hipStream_t stream) {
    const float* q  = (const float*)d_in[0];
    const float* cx = (const float*)d_in[1];
    const float* mk = (const float*)d_in[2];
    const float* mv = (const float*)d_in[3];
    const float* mc = (const float*)d_in[4];
    const float* ts = (const float*)d_in[5];
    float* out = (float*)d_out;

    _Float16* wsp = (_Float16*)d_ws;
    _Float16* KH = wsp;                        // [112][1056]
    _Float16* VT = wsp + KE;                   // [1024][128]

    const int B = in_sizes[0] / DQ;            // 131072

    build_k<<<dim3(17, 112), dim3(64), 0, stream>>>(mk, mc, KH);
    build_vt<<<dim3(512), dim3(256), 0, stream>>>(mv, VT);
    epmem_pipe<<<dim3(B / 64), dim3(256), 0, stream>>>(q, cx, ts, KH, VT, out);
}

// Round 18
// 256.704 us; speedup vs baseline: 1.4335x; 1.0685x over previous
//
#include <hip/hip_runtime.h>

// TrueEpisodicMemory round 18: r14 base (HW-passed, 270us) + ONE change: PV store path.
// Diagnosis: NT stores bypass L2 (no write-combining), and each r14 store instruction
// writes only 64 B per row -> DRAM sees 64-B partial-line writes (WRITE_SIZE +12% RMW
// amplification). Fix: per-step wave-private LDS transpose in the dead P region (4 KB):
// 16 scalar ds_writes + lgkmcnt(0) + 4x b128 reads -> 4 dwordx4 NT stores, each with
// 256-B contiguous runs per row (full 128-B lines, no RMW, 4x fewer store instrs).
// Read-granularity ladder measured: 64B=318, 128B=296, 256B=270us; this applies the
// same octaves to the write side with geometry fixed. All else r14 VERBATIM.
// out[b,:] = softmax_m(q[b]·mk[m] + 0.5*cx[b]·mc[m] + exp(0.1*ts[m])) · mv
// B=131072, M=100 (pad 112/128), D=1024, C=16.

typedef __attribute__((ext_vector_type(8))) _Float16 f16x8;
typedef __attribute__((ext_vector_type(4))) float f32x4;

constexpr int DQ = 1024, CD = 16, MM = 100, KD = 1056, NT = 7;
constexpr size_t KE = (size_t)112 * KD;

// LDS (bytes):
//  QK: Q[2][64 rows][16 slots x16B] @0 (16 KB ea -> 32768); K[3][112][4 slots x16B]
//      @32768 (7168 ea -> 21504; end 54272).
//  PV overlay: P[4 waves][4096] @0 (16 KB; after pa load each wave's 4 KB = transpose
//      tile T[16][64]f32); V[3][64 d][16 slots x16B] @16384 (16384 ea -> end 65536).
constexpr int QBUF = 16384, KOFF = 32768, KBUF = 7168;
constexpr int VOFF = 16384, VBUF = 16384;
constexpr int LDSZ = 65536;

#define WAITV(n) asm volatile("s_waitcnt vmcnt(" #n ")" ::: "memory")

__device__ __forceinline__ void gl16(const void* g, void* l) {
    __builtin_amdgcn_global_load_lds(
        (const __attribute__((address_space(1))) unsigned int*)g,
        (__attribute__((address_space(3))) unsigned int*)l, 16, 0, 0);
}

// ---------------- prologue: fp16 K [112][1056], ctx folded at cols 1024..1039 (r11) ----------
__global__ void build_k(const float* __restrict__ mk, const float* __restrict__ mc,
                        _Float16* __restrict__ KH)
{
    int d = blockIdx.x * 64 + threadIdx.x;
    int m = blockIdx.y;
    if (d >= KD) return;
    float x = 0.f;
    if (m < MM) {
        if (d < DQ)            x = mk[(size_t)m * DQ + d];
        else if (d < DQ + CD)  x = 0.5f * mc[(size_t)m * CD + (d - DQ)];
    }
    KH[(size_t)m * KD + d] = (_Float16)x;
}

// ---------------- prologue: fp16 V^T [1024][128] (cols 100..127 zero) (r11) ----------------
__global__ void build_vt(const float* __restrict__ mv, _Float16* __restrict__ VT)
{
    int idx = blockIdx.x * 256 + threadIdx.x;   // 0..131071
    int d = idx >> 7, m = idx & 127;
    VT[idx] = (m < MM) ? (_Float16)mv[(size_t)m * DQ + d] : (_Float16)0.f;
}

// ---------------- main fused kernel: 256 threads, 64 rows/block ----------------
__global__ __launch_bounds__(256, 2)
void epmem_pipe(const float* __restrict__ q, const float* __restrict__ cx,
                const float* __restrict__ ts,
                const _Float16* __restrict__ KH, const _Float16* __restrict__ VT,
                float* __restrict__ out)
{
    __shared__ __align__(16) char lds[LDSZ];

    const int t = threadIdx.x, w = t >> 6, lane = t & 63;
    const int lr = lane & 15, lk = lane >> 4;
    const int row0 = blockIdx.x * 64;

    float dec[NT];
    #pragma unroll
    for (int nt = 0; nt < NT; ++nt) {
        int m = nt * 16 + lr;
        dec[nt] = (m < MM) ? __expf(0.1f * ts[m]) : 0.f;
    }

    // ---- staging: linear LDS dest; swizzle on GLOBAL source (r14 verbatim) ----
    auto stageQ = [&](int buf, int ms) {            // [64 rows][16 slots], 1024 segs, 4/thread
        char* dst = lds + buf * QBUF;               // each instr: 4 rows x 256 B contiguous
        #pragma unroll
        for (int i = 0; i < 4; ++i) {
            int s = i * 256 + t;                    // row s>>4, phys slot s&15
            int row = s >> 4;
            int logical = (s & 15) ^ (row & 15);
            gl16(q + (size_t)(row0 + row) * DQ + ms * 64 + logical * 4,
                 dst + (i * 256 + w * 64) * 16);
        }
    };
    auto stageQctx = [&](int buf) {                 // [64 rows][4 slots] packed, 256 segs
        char* dst = lds + buf * QBUF;
        gl16(cx + (size_t)(row0 + (t >> 2)) * CD + (t & 3) * 4, dst + (w * 64) * 16);
    };
    auto stageK = [&](int buf, int ks) {            // 448 segs, 7 instrs: w0..w2 x2, w3 x1
        char* dst = lds + KOFF + buf * KBUF;
        for (int i = w; i < 7; i += 4) {
            int s = i * 64 + lane;                  // m s>>2, phys slot s&3
            int m = s >> 2;
            int logical = (s & 3) ^ ((m >> 1) & 3);
            gl16(KH + (size_t)m * KD + ks * 32 + logical * 8, dst + (i * 64) * 16);
        }
    };
    auto stageV = [&](int buf, int c) {             // [64 d][16 slots], 1024 segs, 4/thread
        char* dst = lds + VOFF + buf * VBUF;
        #pragma unroll
        for (int i = 0; i < 4; ++i) {
            int s = i * 256 + t;                    // d s>>4, phys slot s&15
            int d = s >> 4;
            int logical = (s & 15) ^ (d & 15);
            gl16(VT + (size_t)(c * 64 + d) * 128 + logical * 8,
                 dst + (i * 256 + w * 64) * 16);
        }
    };

    f32x4 acc[NT];
    #pragma unroll
    for (int nt = 0; nt < NT; ++nt) acc[nt] = (f32x4){0.f, 0.f, 0.f, 0.f};

    auto qkStep = [&](const char* qx, const char* qy, const char* kb) {
        f32x4 x = *(const f32x4*)qx, y = *(const f32x4*)qy;
        f16x8 ah, al;
        #pragma unroll
        for (int e = 0; e < 4; ++e) {
            _Float16 h = (_Float16)x[e]; ah[e] = h;     al[e] = (_Float16)(x[e] - (float)h);
            h = (_Float16)y[e];          ah[4 + e] = h; al[4 + e] = (_Float16)(y[e] - (float)h);
        }
        #pragma unroll
        for (int nt = 0; nt < NT; ++nt) {
            int m = nt * 16 + lr;
            f16x8 bh = *(const f16x8*)(kb + ((m << 2) + (lk ^ ((lr >> 1) & 3))) * 16);
            acc[nt] = __builtin_amdgcn_mfma_f32_16x16x32_f16(ah, bh, acc[nt], 0, 0, 0);
            acc[nt] = __builtin_amdgcn_mfma_f32_16x16x32_f16(al, bh, acc[nt], 0, 0, 0);
        }
    };

    // ---------- QK^T (r14 verbatim): 32 sub-steps of 32 k-cols + ctx sub-step ----------
    stageQ(0, 0);
    stageK(0, 0); stageK(1, 1);
    if (w < 3) { WAITV(2); } else { WAITV(1); }
    __builtin_amdgcn_s_barrier();

    for (int ss = 0; ss < 32; ++ss) {
        const int ms = ss >> 1, h = ss & 1;
        if (h == 0) {
            if (ms + 1 <= 15)   stageQ((ms + 1) & 1, ms + 1);
            else                stageQctx(0);       // ss == 30
        }
        if (ss <= 30) stageK((ss + 2) % 3, ss + 2);

        const char* base = lds + (ms & 1) * QBUF + (w * 16 + lr) * 256;
        const int u0 = h * 8 + 2 * lk;
        qkStep(base + ((u0 ^ lr) << 4), base + (((u0 + 1) ^ lr) << 4),
               lds + KOFF + (ss % 3) * KBUF);

        if (h == 0) {
            if (ss == 30) { if (w < 3) { WAITV(3); } else { WAITV(2); } }
            else          { if (w < 3) { WAITV(6); } else { WAITV(5); } }
        } else {
            if (ss == 31) { WAITV(0); }
            else          { if (w < 3) { WAITV(2); } else { WAITV(1); } }
        }
        __builtin_amdgcn_s_barrier();
    }
    {   // ctx sub-step (ss=32): r14 verbatim
        f16x8 ah, al;
        if (lk < 2) {
            const char* base = lds + (w * 16 + lr) * 64;
            f32x4 x = *(const f32x4*)(base + (2 * lk) * 16);
            f32x4 y = *(const f32x4*)(base + (2 * lk + 1) * 16);
            #pragma unroll
            for (int e = 0; e < 4; ++e) {
                _Float16 h = (_Float16)x[e]; ah[e] = h;     al[e] = (_Float16)(x[e] - (float)h);
                h = (_Float16)y[e];          ah[4 + e] = h; al[4 + e] = (_Float16)(y[e] - (float)h);
            }
        } else {
            #pragma unroll
            for (int e = 0; e < 8; ++e) { ah[e] = (_Float16)0.f; al[e] = (_Float16)0.f; }
        }
        const char* kb = lds + KOFF + 2 * KBUF;
        #pragma unroll
        for (int nt = 0; nt < NT; ++nt) {
            int m = nt * 16 + lr;
            f16x8 bh = *(const f16x8*)(kb + ((m << 2) + (lk ^ ((lr >> 1) & 3))) * 16);
            acc[nt] = __builtin_amdgcn_mfma_f32_16x16x32_f16(ah, bh, acc[nt], 0, 0, 0);
            acc[nt] = __builtin_amdgcn_mfma_f32_16x16x32_f16(al, bh, acc[nt], 0, 0, 0);
        }
    }
    __syncthreads();                            // QK LDS dead; P/V may overlay

    stageV(0, 0); stageV(1, 1);                 // V latency hides under softmax

    // ---------- softmax, fully in-register (r14 verbatim; Pb @ w*4096) ----------
    char* Pb = lds + w * 4096;
    {
        float rm[4] = {-3e38f, -3e38f, -3e38f, -3e38f};
        #pragma unroll
        for (int nt = 0; nt < NT; ++nt) {
            int m = nt * 16 + lr;
            #pragma unroll
            for (int r = 0; r < 4; ++r) {
                float s = (m < MM) ? (acc[nt][r] + dec[nt]) : -3e38f;
                acc[nt][r] = s;
                rm[r] = fmaxf(rm[r], s);
            }
        }
        #pragma unroll
        for (int r = 0; r < 4; ++r)
            #pragma unroll
            for (int off = 1; off < 16; off <<= 1)
                rm[r] = fmaxf(rm[r], __shfl_xor(rm[r], off));
        float rs[4] = {0.f, 0.f, 0.f, 0.f};
        #pragma unroll
        for (int nt = 0; nt < NT; ++nt)
            #pragma unroll
            for (int r = 0; r < 4; ++r) {
                float e = __expf(acc[nt][r] - rm[r]);
                acc[nt][r] = e;
                rs[r] += e;
            }
        #pragma unroll
        for (int r = 0; r < 4; ++r)
            #pragma unroll
            for (int off = 1; off < 16; off <<= 1)
                rs[r] += __shfl_xor(rs[r], off);
        #pragma unroll
        for (int r = 0; r < 4; ++r) {
            float inv = 1.f / rs[r];
            int row = 4 * lk + r;
            #pragma unroll
            for (int nt = 0; nt < NT; ++nt)
                *(_Float16*)(Pb + row * 256 + (((nt * 2 + (lr >> 3)) ^ row) & 15) * 16
                             + (lr & 7) * 2) = (_Float16)(acc[nt][r] * inv);
        }
    }
    if (lane < 32) {                            // zero-pad P cols 112..127 (slots 14,15)
        int row = lane >> 1, sl = 14 + (lane & 1);
        uint4 z = {0u, 0u, 0u, 0u};
        *(uint4*)(Pb + row * 256 + ((sl ^ row) & 15) * 16) = z;
    }
    WAITV(4);                                   // V(0) resident; V(1) in flight
    __builtin_amdgcn_s_barrier();

    // ---------- PV: 16 steps of 64 cols; transpose-tile wide-store path ----------
    f16x8 pa[4];
    #pragma unroll
    for (int k4 = 0; k4 < 4; ++k4)
        pa[k4] = *(const f16x8*)(Pb + lr * 256 + (((k4 * 4 + lk) ^ lr) & 15) * 16);
    asm volatile("s_waitcnt lgkmcnt(0)" ::: "memory");  // pa read done before T overwrites Pb

    float* T = (float*)Pb;                      // wave-private transpose tile [16][64] f32

    for (int c = 0; c < 16; ++c) {
        if (c + 2 < 16) stageV((c + 2) % 3, c + 2);
        const char* vb = lds + VOFF + (c % 3) * VBUF;
        f32x4 o0 = {0.f,0.f,0.f,0.f}, o1 = {0.f,0.f,0.f,0.f};
        f32x4 o2 = {0.f,0.f,0.f,0.f}, o3 = {0.f,0.f,0.f,0.f};
        #pragma unroll
        for (int k4 = 0; k4 < 4; ++k4) {
            const char* vb2 = vb + (((k4 * 4 + lk) ^ lr) & 15) * 16;
            f16x8 b0 = *(const f16x8*)(vb2 + lr * 256);          // d-local = lr
            f16x8 b1 = *(const f16x8*)(vb2 + (16 + lr) * 256);
            f16x8 b2 = *(const f16x8*)(vb2 + (32 + lr) * 256);
            f16x8 b3 = *(const f16x8*)(vb2 + (48 + lr) * 256);   // (d&15)=lr for all
            o0 = __builtin_amdgcn_mfma_f32_16x16x32_f16(pa[k4], b0, o0, 0, 0, 0);
            o1 = __builtin_amdgcn_mfma_f32_16x16x32_f16(pa[k4], b1, o1, 0, 0, 0);
            o2 = __builtin_amdgcn_mfma_f32_16x16x32_f16(pa[k4], b2, o2, 0, 0, 0);
            o3 = __builtin_amdgcn_mfma_f32_16x16x32_f16(pa[k4], b3, o3, 0, 0, 0);
        }
        // transpose: o[n][r] -> T[4*lk+r][n*16+lr]  (scalar ds_writes, 2/bank = free)
        #pragma unroll
        for (int r = 0; r < 4; ++r) {
            T[(4 * lk + r) * 64 +      lr] = o0[r];
            T[(4 * lk + r) * 64 + 16 + lr] = o1[r];
            T[(4 * lk + r) * 64 + 32 + lr] = o2[r];
            T[(4 * lk + r) * 64 + 48 + lr] = o3[r];
        }
        asm volatile("s_waitcnt lgkmcnt(0)" ::: "memory");  // wave-private: no barrier
        // wide stores: instr k covers 4 rows x 256-B contiguous runs (full 128-B lines)
        #pragma unroll
        for (int k = 0; k < 4; ++k) {
            f32x4 v = *(const f32x4*)(T + (4 * k + lk) * 64 + 4 * lr);
            __builtin_nontemporal_store(v,
                (f32x4*)&out[(size_t)(row0 + w * 16 + 4 * k + lk) * DQ + c * 64 + 4 * lr]);
        }
        // Ledger (induction; step issues: stage 4 (c+2<16) then 4 stores):
        //  c=0: need V(1); newer = V(2) 4 + stores(0) 4 -> WAITV(8)
        //  1<=c<=13: need V(c+1); newer = stores(c-1) 4 + V(c+2) 4 + stores(c) 4 -> 12
        //  c=14: no stage; need V(15); newer = stores(13) 4 + stores(14) 4 -> 8
        if (c == 0)       { WAITV(8); }
        else if (c <= 13) { WAITV(12); }
        else if (c == 14) { WAITV(8); }
        if (c < 15) __builtin_amdgcn_s_barrier();
    }
}

extern "C" void kernel_launch(void* const* d_in, const int* in_sizes, int n_in,
                              void* d_out, int out_size, void* d_ws, size_t ws_size,
                              hipStream_t stream) {
    const float* q  = (const float*)d_in[0];
    const float* cx = (const float*)d_in[1];
    const float* mk = (const float*)d_in[2];
    const float* mv = (const float*)d_in[3];
    const float* mc = (const float*)d_in[4];
    const float* ts = (const float*)d_in[5];
    float* out = (float*)d_out;

    _Float16* wsp = (_Float16*)d_ws;
    _Float16* KH = wsp;                        // [112][1056]
    _Float16* VT = wsp + KE;                   // [1024][128]

    const int B = in_sizes[0] / DQ;            // 131072

    build_k<<<dim3(17, 112), dim3(64), 0, stream>>>(mk, mc, KH);
    build_vt<<<dim3(512), dim3(256), 0, stream>>>(mv, VT);
    epmem_pipe<<<dim3(B / 64), dim3(256), 0, stream>>>(q, cx, ts, KH, VT, out);
}